// Round 27
// baseline (9283.192 us; speedup 1.0000x reference)
//
#include <hip/hip_runtime.h>

// Farthest point sampling, B=32, N=32768, npoint=4096.
// R27: kill the 256KB/step xy stream (R26 showed memory-ingest-bound:
// 4096cyc of L1/L2 path vs 2240cyc VALU). px/py now live in AGPRs under
// EXPLICIT control: v_accvgpr_write once at init, volatile v_accvgpr_read
// (+2 inst/pt) in the loop. Compiler-chosen parking was bad because it
// parked RMW-hot dist[] too; here dist[32] stays in arch VGPRs and AGPRs
// hold only read-only coords. volatile stops LICM from hoisting reads into
// permanent VGPR copies (which would spill). z stays in 128KB static LDS
// (separate LDS pipe). Centroid = R22's global broadcast read. No ws.
// Reduce chassis (R22/R26 proven): DPP wave max (lane63) -> 32-bit LDS
// atomicMax -> B1 -> phase-B constant-index rescan of dist[] (candidates
// only) -> atomicMin global index -> B2 -> 3-slot rotation reset.
// First-occurrence argmax preserved (descending rescan ends at smallest i;
// min across candidates). PASSING arithmetic (R6, bit-exact):
// d = fmaf(dz,dz, fmaf(dx,dx, dy*dy)), contract(off), fminf chain.
// Output float32: [B*NPOINT] idx, [B*NPOINT*3] coords.

#define BATCH  32
#define NPTS   32768
#define NPOINT 4096
#define NT     1024
#define NCH    16            // chunks of 2: 32 points per thread

#define DPP1(x, ctrl, rm) __builtin_amdgcn_update_dpp((x), (x), (ctrl), (rm), 0xf, false)

__device__ __forceinline__ float wave_max_dpp(float v) {
    unsigned int u = __float_as_uint(v);
    u = __float_as_uint(fmaxf(__uint_as_float(u), __uint_as_float(DPP1(u, 0xB1, 0xf))));
    u = __float_as_uint(fmaxf(__uint_as_float(u), __uint_as_float(DPP1(u, 0x4E, 0xf))));
    u = __float_as_uint(fmaxf(__uint_as_float(u), __uint_as_float(DPP1(u, 0x141, 0xf))));
    u = __float_as_uint(fmaxf(__uint_as_float(u), __uint_as_float(DPP1(u, 0x140, 0xf))));
    u = __float_as_uint(fmaxf(__uint_as_float(u), __uint_as_float(DPP1(u, 0x142, 0xa))));
    u = __float_as_uint(fmaxf(__uint_as_float(u), __uint_as_float(DPP1(u, 0x143, 0xc))));
    return __uint_as_float(u);   // lane 63 = wave max
}

// Explicit AGPR park/fetch (read-only data; dist stays in arch VGPRs).
#define AWRITE(dst, src) \
    asm volatile("v_accvgpr_write_b32 %0, %1" : "=a"(dst) : "v"(src))
#define AREAD(dst, src) \
    asm volatile("v_accvgpr_read_b32 %0, %1" : "=v"(dst) : "a"(src))

__global__ __launch_bounds__(NT, 1) void fps_kernel(
    const float* __restrict__ xyz,   // [B, N, 3] float32
    float* __restrict__ out_idx,     // [B, NPOINT]
    float* __restrict__ out_xyz)     // [B, NPOINT, 3]
{
#pragma clang fp contract(off)
    __shared__ float pz_lds[NPTS];               // 128 KB static
    __shared__ unsigned int s_val[3];            // dist bits (>=0, monotone)
    __shared__ int s_idx[3];                     // winning global index

    const int b   = blockIdx.x;
    const int tid = threadIdx.x;
    const float* base = xyz + (size_t)b * NPTS * 3;

    float dist[NCH * 2];
    float ax[NCH * 2], ay[NCH * 2];              // AGPR-resident coords
#pragma unroll
    for (int c = 0; c < NCH; ++c) {
#pragma unroll
        for (int j = 0; j < 2; ++j) {
            const int i = c * 2 + j;
            const int g = c * 2048 + 2 * tid + j;
            const float x = base[g * 3 + 0];
            const float y = base[g * 3 + 1];
            pz_lds[g] = base[g * 3 + 2];
            AWRITE(ax[i], x);
            AWRITE(ay[i], y);
            dist[i] = 1e10f;
        }
    }
    if (tid == 0) {
        s_val[0] = 0u; s_val[1] = 0u; s_val[2] = 0u;
        s_idx[0] = 0x7fffffff; s_idx[1] = 0x7fffffff; s_idx[2] = 0x7fffffff;
    }
    __syncthreads();                       // pz_lds + slots ready

    int w = 1;   // RAN=False seed
    int p = 0;   // rotating slot index k%3

    for (int k = 0; k < NPOINT; ++k) {
        // Broadcast centroid from global (same addr across lanes, L2-hot).
        const float cx = base[w * 3 + 0];
        const float cy = base[w * 3 + 1];
        const float cz = base[w * 3 + 2];
        if (tid == 0) {
            out_idx[(size_t)b * NPOINT + k] = (float)w;
            float* o = out_xyz + ((size_t)b * NPOINT + k) * 3;
            o[0] = cx; o[1] = cy; o[2] = cz;
        }

        // Distance update; VALUE-only tracking. Coords fetched from AGPR
        // (2 inst/pt), z from LDS pipe, dist RMW in arch VGPRs.
        float best = -1.0f;
#pragma unroll
        for (int c = 0; c < NCH; ++c) {
            float x0, y0, x1, y1;
            AREAD(x0, ax[c * 2 + 0]);
            AREAD(y0, ay[c * 2 + 0]);
            AREAD(x1, ax[c * 2 + 1]);
            AREAD(y1, ay[c * 2 + 1]);
            const float2 zz = *(const float2*)&pz_lds[c * 2048 + 2 * tid];
            {   // j = 0
                const float dx = x0 - cx;
                const float dy = y0 - cy;
                const float dz = zz.x - cz;
                const float d  = fmaf(dz, dz, fmaf(dx, dx, dy * dy));
                const float nd = fminf(dist[c * 2 + 0], d);
                dist[c * 2 + 0] = nd;
                best = fmaxf(best, nd);
            }
            {   // j = 1
                const float dx = x1 - cx;
                const float dy = y1 - cy;
                const float dz = zz.y - cz;
                const float d  = fmaf(dz, dz, fmaf(dx, dx, dy * dy));
                const float nd = fminf(dist[c * 2 + 1], d);
                dist[c * 2 + 1] = nd;
                best = fmaxf(best, nd);
            }
        }

        // Phase A: value-only wave max via DPP; lane 63 publishes.
        const float m = wave_max_dpp(best);
        if ((tid & 63) == 63)
            atomicMax(&s_val[p], __float_as_uint(m));
        __syncthreads();                   // B1: block max known
        const float M = __uint_as_float(s_val[p]);

        // Phase B (rare, exec-masked): candidates rescan dist[] for the
        // FIRST ==M (constant indices only) and publish the global index.
        if (best == M) {
            int li = 63;
#pragma unroll
            for (int i = 31; i >= 0; --i)
                if (dist[i] == M) li = i;          // ends at smallest i
            const int bi = (li >> 1) * 2048 + 2 * tid + (li & 1);
            atomicMin(&s_idx[p], bi);
        }
        __syncthreads();                   // B2: winning index known
        w = s_idx[p];
        // Reset slot for step k+2 (barriers of step k+1 order this write
        // before that slot's next atomics; its readers finished at k-1).
        const int pn2 = (p >= 1) ? (p - 1) : 2;   // (k+2)%3
        if (tid == 0) { s_val[pn2] = 0u; s_idx[pn2] = 0x7fffffff; }
        p = (p == 2) ? 0 : (p + 1);
    }
}

extern "C" void kernel_launch(void* const* d_in, const int* in_sizes, int n_in,
                              void* d_out, int out_size, void* d_ws, size_t ws_size,
                              hipStream_t stream) {
    const float* xyz = (const float*)d_in[0];
    float* out = (float*)d_out;
    float* out_idx = out;                              // B*NPOINT floats
    float* out_xyz = out + (size_t)BATCH * NPOINT;     // B*NPOINT*3 floats

    fps_kernel<<<BATCH, NT, 0, stream>>>(xyz, out_idx, out_xyz);
}